// Round 3
// baseline (142.243 us; speedup 1.0000x reference)
//
#include <hip/hip_runtime.h>

// Reprojection residual for bundle adjustment.
// out[i] = project(points_3d[pt_idx[i]], camera_params[cam_idx[i]]) - points_2d[i]
//
// NUMERICS: the harness reference (ref=np) is evaluated in float64; the output
// is amplified ~proj^5 with |Z| down to ~1e-4 (catastrophic cancellation), so a
// fp32 evaluation intrinsically deviates ~3-5% at the worst element (> the 2%
// threshold). We therefore compute the whole projection in double precision
// (error ~1e-11 relative) and round only the final residual to fp32.
//
// Inputs (setup_inputs order):
//   d_in[0] points_2d      float32 (N_OBS, 2)
//   d_in[1] camera_indices int32   (N_OBS,)
//   d_in[2] point_indices  int32   (N_OBS,)
//   d_in[3] camera_params  float32 (N_CAM, 10)  [qw qx qy qz tx ty tz f k1 k2]
//   d_in[4] points_3d      float32 (N_PTS, 3)
// Output: float32 (N_OBS, 2)

__device__ __forceinline__ float2 project_one(
    int ci, int pi,
    const float* __restrict__ cams,
    const float* __restrict__ pts,
    float2 obs)
{
    // camera params: 40 bytes, 8-byte aligned -> five float2 loads
    const float2* c2 = reinterpret_cast<const float2*>(cams + (size_t)ci * 10);
    float2 c01 = c2[0];  // qw qx
    float2 c23 = c2[1];  // qy qz
    float2 c45 = c2[2];  // tx ty
    float2 c67 = c2[3];  // tz f
    float2 c89 = c2[4];  // k1 k2

    const float* p = pts + (size_t)pi * 3;
    double px = (double)p[0], py = (double)p[1], pz = (double)p[2];

    double qw = (double)c01.x, qx = (double)c01.y;
    double qy = (double)c23.x, qz = (double)c23.y;

    // normalize quaternion
    double nrm2 = qw * qw + qx * qx + qy * qy + qz * qz;
    double s = 1.0 / sqrt(nrm2);
    double w  = qw * s;
    double vx = qx * s, vy = qy * s, vz = qz * s;

    // t = cross(v, p) + w * p
    double tx = (vy * pz - vz * py) + w * px;
    double ty = (vz * px - vx * pz) + w * py;
    double tz = (vx * py - vy * px) + w * pz;

    // rotated = p + 2 * cross(v, t); then translate
    double X = (px + 2.0 * (vy * tz - vz * ty)) + (double)c45.x;
    double Y = (py + 2.0 * (vz * tx - vx * tz)) + (double)c45.y;
    double Z = (pz + 2.0 * (vx * ty - vy * tx)) + (double)c67.x;

    // proj = -[X,Y] / Z
    double rz  = 1.0 / Z;
    double prx = -X * rz;
    double pry = -Y * rz;

    double f  = (double)c67.y;
    double k1 = (double)c89.x, k2 = (double)c89.y;

    double nn = prx * prx + pry * pry;
    double r  = 1.0 + k1 * nn + k2 * nn * nn;
    double rf = r * f;

    float2 o;
    o.x = (float)(prx * rf - (double)obs.x);
    o.y = (float)(pry * rf - (double)obs.y);
    return o;
}

__global__ __launch_bounds__(256) void reproj_kernel(
    const float2* __restrict__ p2d,
    const int*    __restrict__ cam_idx,
    const int*    __restrict__ pt_idx,
    const float*  __restrict__ cams,
    const float*  __restrict__ pts,
    float2*       __restrict__ out,
    int n)  // n = number of observations
{
    int t = blockIdx.x * blockDim.x + threadIdx.x;
    int i = t * 2;
    if (i + 1 < n) {
        // vectorized pair: int2 indices, float4 obs/out
        int2 ci = *reinterpret_cast<const int2*>(cam_idx + i);
        int2 pi = *reinterpret_cast<const int2*>(pt_idx + i);
        float4 ob = *reinterpret_cast<const float4*>(p2d + i);
        float2 o0 = project_one(ci.x, pi.x, cams, pts, make_float2(ob.x, ob.y));
        float2 o1 = project_one(ci.y, pi.y, cams, pts, make_float2(ob.z, ob.w));
        float4 ov = make_float4(o0.x, o0.y, o1.x, o1.y);
        *reinterpret_cast<float4*>(out + i) = ov;
    } else if (i < n) {
        int ci = cam_idx[i];
        int pi = pt_idx[i];
        float2 ob = p2d[i];
        out[i] = project_one(ci, pi, cams, pts, ob);
    }
}

extern "C" void kernel_launch(void* const* d_in, const int* in_sizes, int n_in,
                              void* d_out, int out_size, void* d_ws, size_t ws_size,
                              hipStream_t stream) {
    const float2* p2d     = (const float2*)d_in[0];
    const int*    cam_idx = (const int*)d_in[1];
    const int*    pt_idx  = (const int*)d_in[2];
    const float*  cams    = (const float*)d_in[3];
    const float*  pts     = (const float*)d_in[4];
    float2*       out     = (float2*)d_out;

    int n = in_sizes[1];  // N_OBS (camera_indices element count)

    int threads = 256;
    int elems_per_block = threads * 2;
    int blocks = (n + elems_per_block - 1) / elems_per_block;

    reproj_kernel<<<blocks, threads, 0, stream>>>(p2d, cam_idx, pt_idx, cams, pts, out, n);
}